// Round 1
// baseline (1887.221 us; speedup 1.0000x reference)
//
#include <hip/hip_runtime.h>
#include <stdint.h>

// Persistent-kernel RNN: 256 wgs (1/CU), W_hh bf16 resident in LDS (16 j-slices),
// batch split 16 ways; h exchanged via Infinity Cache with sc0 sc1 ops + per-group flags.

#define BATCH 512
#define SEQ   256
#define HID   1024
#define CLS   128

#define GB 16          // batch groups
#define GJ 16          // hidden slices
#define BT 32          // batch rows per wg
#define JT 64          // hidden cols per wg
#define KC 256         // k-chunk staged per iteration
#define WSTR 1028      // W LDS row stride in halves (1024 + 4 pad -> 2-way banks, 8B aligned)
#define SSTR 260       // stage row stride in halves (256 + 4 pad)
#define SMEM_BYTES ((JT * WSTR + BT * SSTR) * 2)   // 131584 + 16640 = 148224 B
#define HBUF_HALVES (BATCH * HID)                  // 524288 halves = 1 MB per buffer

typedef __attribute__((ext_vector_type(8))) short  bf16x8;
typedef __attribute__((ext_vector_type(4))) short  s16x4;
typedef __attribute__((ext_vector_type(4))) float  f32x4;
typedef __attribute__((ext_vector_type(4))) int    i32x4;
typedef __attribute__((ext_vector_type(2))) unsigned int u32x2;

__device__ __forceinline__ unsigned short f2bf(float f) {
  unsigned int u = __float_as_uint(f);
  u = (u + 0x7FFFu + ((u >> 16) & 1u)) >> 16;   // RNE
  return (unsigned short)u;
}
__device__ __forceinline__ float b2f(short h) {
  return __uint_as_float(((unsigned int)(unsigned short)h) << 16);
}

// device-coherent (IC-level) accesses: sc0 sc1 bypass L1 and per-XCD L2
__device__ __forceinline__ void store_flag(int* p, int v) {
  asm volatile("global_store_dword %0, %1, off sc0 sc1" :: "v"(p), "v"(v) : "memory");
}
__device__ __forceinline__ int load_flag(const int* p) {
  int v;
  asm volatile("global_load_dword %0, %1, off sc0 sc1\n\t"
               "s_waitcnt vmcnt(0)" : "=v"(v) : "v"(p) : "memory");
  return v;
}
__device__ __forceinline__ void store_bf16(void* p, int v) {
  asm volatile("global_store_short %0, %1, off sc0 sc1" :: "v"(p), "v"(v) : "memory");
}
__device__ __forceinline__ void waitcnt0() {
  asm volatile("s_waitcnt vmcnt(0)" ::: "memory");
}
// issue 4x dwordx4 coherent loads (64 B/thread), no wait -> overlap with MFMA
__device__ __forceinline__ void issue4(const void* p, i32x4& a, i32x4& b, i32x4& c, i32x4& d) {
  asm volatile(
    "global_load_dwordx4 %0, %4, off sc0 sc1\n\t"
    "global_load_dwordx4 %1, %4, off offset:128 sc0 sc1\n\t"
    "global_load_dwordx4 %2, %4, off offset:256 sc0 sc1\n\t"
    "global_load_dwordx4 %3, %4, off offset:384 sc0 sc1"
    : "=&v"(a), "=&v"(b), "=&v"(c), "=&v"(d)
    : "v"(p) : "memory");
}
__device__ __forceinline__ void wr16(short* p, i32x4 v) {  // 16 B to LDS as 2x b64 (8B-aligned rows)
  u32x2 lo, hi;
  lo.x = (unsigned)v.x; lo.y = (unsigned)v.y;
  hi.x = (unsigned)v.z; hi.y = (unsigned)v.w;
  *(u32x2*)p = lo;
  *(u32x2*)(p + 4) = hi;
}
__device__ __forceinline__ bf16x8 ld8(const short* p) {    // 8 bf16 from LDS as 2x b64
  union { bf16x8 v8; s16x4 h[2]; } u;
  u.h[0] = *(const s16x4*)p;
  u.h[1] = *(const s16x4*)(p + 4);
  return u.v8;
}
__device__ __forceinline__ float tanh_fast(float z) {
  float e = __expf(2.f * z);
  return 1.f - 2.f / (e + 1.f);     // saturates correctly for |z| large
}

__global__ void __launch_bounds__(256, 1)
rnn_persistent(const float* __restrict__ x, const float* __restrict__ Whx,
               const float* __restrict__ Whh, const float* __restrict__ bh,
               const float* __restrict__ Wph, const float* __restrict__ bp,
               float* __restrict__ out, unsigned short* hbuf, int* flags)
{
  extern __shared__ short smem[];
  short* sW = smem;                 // [JT][WSTR] bf16 W_hh slice, persistent
  short* sS = smem + JT * WSTR;     // [BT][SSTR] bf16 h k-chunk stage

  const int tid  = threadIdx.x;
  const int bg   = blockIdx.x & 15;   // same-bg wgs land on same XCD under round-robin (perf only)
  const int jg   = blockIdx.x >> 4;
  const int lane = tid & 63;
  const int wv   = tid >> 6;          // wave = n-tile (16 cols each)
  const int l15  = lane & 15;
  const int quad = lane >> 4;

  // ---- stage W_hh[jg*64 .. +64)[0..1024) into LDS as bf16 ----
  {
    const int jr = tid >> 2;          // 0..63
    const int kq = tid & 3;           // 0..3
    const float* src = Whh + (jg * JT + jr) * HID + kq * 256;
    short* dst = sW + jr * WSTR + kq * 256;
#pragma unroll 4
    for (int i = 0; i < 64; ++i) {
      float4 f = *(const float4*)(src + i * 4);
      s16x4 h4;
      h4.x = (short)f2bf(f.x); h4.y = (short)f2bf(f.y);
      h4.z = (short)f2bf(f.z); h4.w = (short)f2bf(f.w);
      *(s16x4*)(dst + i * 4) = h4;
    }
  }

  // per-lane output column j (fixed across the whole run)
  const int j = jg * JT + wv * 16 + l15;
  const float whx = Whx[j];
  const float bhv = bh[j];
  const int grow0 = bg * BT + quad * 4;   // global batch row base for C-frag (m=0)

  // staging thread mapping: 64 B per thread per chunk
  const int sr  = tid >> 3;               // 0..31 stage row
  const int seg = tid & 7;                // 0..7

  int* myflags = flags + bg * 64;         // 16 flags, one 64B line per bg

  for (int t = 0; t < SEQ; ++t) {
    const unsigned short* hin = hbuf + ((t + 1) & 1) * HBUF_HALVES;  // output of t-1
    unsigned short*      hout = hbuf + (t & 1) * HBUF_HALVES;

    f32x4 acc0 = {0.f, 0.f, 0.f, 0.f};
    f32x4 acc1 = {0.f, 0.f, 0.f, 0.f};

    if (t > 0) {
      // wait until all 16 peers of this batch-group finished step t-1.
      // flag semantics: flag == s  <=>  step s-1 stores are IC-visible.
      // 0xAA poison reads as negative int -> "not ready": no init needed.
      if (tid < GJ) {
        while (load_flag(myflags + tid) < t) {}
      }
      __syncthreads();

      const char* lbase = (const char*)(hin + (bg * BT + sr) * HID) + seg * 16;
      short* sdst = sS + sr * SSTR + seg * 8;
      i32x4 p0, p1, p2, p3;
      issue4(lbase, p0, p1, p2, p3);     // chunk 0 in flight

      for (int c = 0; c < 4; ++c) {
        __syncthreads();                  // previous chunk fully consumed
        waitcnt0();                       // chunk-c data arrived
        wr16(sdst,       p0);
        wr16(sdst + 64,  p1);
        wr16(sdst + 128, p2);
        wr16(sdst + 192, p3);
        if (c < 3) issue4(lbase + (c + 1) * 512, p0, p1, p2, p3);  // prefetch next chunk
        __syncthreads();                  // stage visible to all waves

        const short* Brow  = sW + (wv * 16 + l15) * WSTR + c * KC + quad * 8;
        const short* Arow0 = sS + l15 * SSTR + quad * 8;
        const short* Arow1 = Arow0 + 16 * SSTR;
#pragma unroll
        for (int ks = 0; ks < 8; ++ks) {
          bf16x8 bfr = ld8(Brow  + ks * 32);   // B[k][n] = W_hh[j][k]
          bf16x8 a0  = ld8(Arow0 + ks * 32);   // A[m][k] = h[row][k]
          bf16x8 a1  = ld8(Arow1 + ks * 32);
          acc0 = __builtin_amdgcn_mfma_f32_16x16x32_bf16(a0, bfr, acc0, 0, 0, 0);
          acc1 = __builtin_amdgcn_mfma_f32_16x16x32_bf16(a1, bfr, acc1, 0, 0, 0);
        }
      }
    }

    // epilogue: z = acc + x[b,t]*Whx[j] + bh[j]; h = tanh(z); coherent bf16 store
    {
      const float* xp = x + grow0 * SEQ + t;
      unsigned short* op = hout + grow0 * HID + j;
#pragma unroll
      for (int rg = 0; rg < 4; ++rg) {
        float z0 = acc0[rg] + xp[rg * SEQ] * whx + bhv;
        store_bf16(op + rg * HID, (int)f2bf(tanh_fast(z0)));
        float z1 = acc1[rg] + xp[(16 + rg) * SEQ] * whx + bhv;
        store_bf16(op + (16 + rg) * HID, (int)f2bf(tanh_fast(z1)));
      }
    }
    waitcnt0();          // this thread's h stores are IC-visible
    __syncthreads();     // all threads of wg done
    if (tid == 0) store_flag(myflags + jg, t + 1);
  }

  // ---- output head: out[b, jg*8+cc] = h_last . W_ph[c] + b_p ----
  if (tid < GJ) {
    while (load_flag(myflags + tid) < SEQ) {}
  }
  __syncthreads();

  const unsigned short* hlast = hbuf + ((SEQ - 1) & 1) * HBUF_HALVES;
  const int cc = tid & 7;
  const int cg = jg * 8 + cc;
  const int hr = tid >> 3;             // == sr
  float acc = 0.f;
  const char* lbase = (const char*)(hlast + (bg * BT + sr) * HID) + seg * 16;
  short* sdst = sS + sr * SSTR + seg * 8;
  for (int c = 0; c < 4; ++c) {
    __syncthreads();
    i32x4 p0, p1, p2, p3;
    issue4(lbase + c * 512, p0, p1, p2, p3);
    waitcnt0();
    wr16(sdst, p0); wr16(sdst + 64, p1); wr16(sdst + 128, p2); wr16(sdst + 192, p3);
    __syncthreads();
    const float* wp = Wph + cg * HID + c * KC;
    const short* hs = sS + hr * SSTR;
#pragma unroll 8
    for (int k4 = 0; k4 < 64; ++k4) {
      float4 w  = *(const float4*)(wp + k4 * 4);
      s16x4 hv  = *(const s16x4*)(hs + k4 * 4);
      acc += b2f(hv.x) * w.x + b2f(hv.y) * w.y + b2f(hv.z) * w.z + b2f(hv.w) * w.w;
    }
  }
  out[(bg * BT + hr) * CLS + cg] = acc + bp[cg];
}

extern "C" void kernel_launch(void* const* d_in, const int* in_sizes, int n_in,
                              void* d_out, int out_size, void* d_ws, size_t ws_size,
                              hipStream_t stream) {
  const float* x   = (const float*)d_in[0];
  const float* Whx = (const float*)d_in[1];
  const float* Whh = (const float*)d_in[2];
  const float* bh  = (const float*)d_in[3];
  const float* Wph = (const float*)d_in[4];
  const float* bp  = (const float*)d_in[5];
  float* out = (float*)d_out;

  // ws layout: h double-buffer (2 x 1 MB bf16) then flags (16 groups x 64B line)
  unsigned short* hbuf = (unsigned short*)d_ws;
  int* flags = (int*)((char*)d_ws + (size_t)2 * HBUF_HALVES * 2);

  // 148224 B dynamic LDS (>64 KB needs the attribute; gfx950 has 160 KB/CU)
  hipFuncSetAttribute(reinterpret_cast<const void*>(rnn_persistent),
                      hipFuncAttributeMaxDynamicSharedMemorySize, SMEM_BYTES);

  rnn_persistent<<<dim3(GB * GJ), dim3(256), SMEM_BYTES, stream>>>(
      x, Whx, Whh, bh, Wph, bp, out, hbuf, flags);
}

// Round 2
// 1120.395 us; speedup vs baseline: 1.6844x; 1.6844x over previous
//
#include <hip/hip_runtime.h>
#include <stdint.h>

// Persistent-kernel RNN: 256 wgs (1/CU), W_hh bf16 resident in LDS (16 j-slices),
// batch split 16 ways; h exchanged via IC with sc0 sc1 + per-group flags.
// R2: raw s_barrier (lgkm-only drain), all-chunks-upfront loads with counted
// vmcnt waits, coalesced h store via LDS exchange.

#define BATCH 512
#define SEQ   256
#define HID   1024
#define CLS   128

#define GB 16          // batch groups
#define GJ 16          // hidden slices
#define BT 32          // batch rows per wg
#define JT 64          // hidden cols per wg
#define KC 256         // k-chunk per stage buffer fill
#define WSTR 1028      // W LDS row stride (halves): 2-way banks, 8B aligned
#define SSTR 260       // stage row stride (halves)
#define HSTR 68        // h-store exchange row stride (halves)
#define SMEM_BYTES ((JT * WSTR + BT * SSTR) * 2)   // 148224 B
#define HBUF_HALVES (BATCH * HID)                  // 1 MB per buffer

typedef __attribute__((ext_vector_type(8))) short  bf16x8;
typedef __attribute__((ext_vector_type(4))) short  s16x4;
typedef __attribute__((ext_vector_type(4))) float  f32x4;
typedef __attribute__((ext_vector_type(4))) int    i32x4;
typedef __attribute__((ext_vector_type(2))) unsigned int u32x2;

__device__ __forceinline__ unsigned short f2bf(float f) {
  unsigned int u = __float_as_uint(f);
  u = (u + 0x7FFFu + ((u >> 16) & 1u)) >> 16;   // RNE
  return (unsigned short)u;
}
__device__ __forceinline__ float b2f(short h) {
  return __uint_as_float(((unsigned int)(unsigned short)h) << 16);
}

// ---- device-coherent (IC) accesses ----
__device__ __forceinline__ void store_flag(int* p, int v) {
  asm volatile("global_store_dword %0, %1, off sc0 sc1" :: "v"(p), "v"(v) : "memory");
}
__device__ __forceinline__ int load_flag(const int* p) {
  int v;
  asm volatile("global_load_dword %0, %1, off sc0 sc1\n\t"
               "s_waitcnt vmcnt(0)" : "=v"(v) : "v"(p) : "memory");
  return v;
}
__device__ __forceinline__ void store16(void* p, i32x4 v) {
  asm volatile("global_store_dwordx4 %0, %1, off sc0 sc1" :: "v"(p), "v"(v) : "memory");
}
__device__ __forceinline__ void waitcnt0() {
  asm volatile("s_waitcnt vmcnt(0)" ::: "memory");
}
// raw workgroup barrier: drains LDS ops only — global loads stay in flight
__device__ __forceinline__ void barrier_lgkm() {
  asm volatile("s_waitcnt lgkmcnt(0)\n\ts_barrier" ::: "memory");
}
// issue 4x dwordx4 coherent loads (64 B/thread), no wait
__device__ __forceinline__ void issue4(const void* p, i32x4& a, i32x4& b, i32x4& c, i32x4& d) {
  asm volatile(
    "global_load_dwordx4 %0, %4, off sc0 sc1\n\t"
    "global_load_dwordx4 %1, %4, off offset:128 sc0 sc1\n\t"
    "global_load_dwordx4 %2, %4, off offset:256 sc0 sc1\n\t"
    "global_load_dwordx4 %3, %4, off offset:384 sc0 sc1"
    : "=&v"(a), "=&v"(b), "=&v"(c), "=&v"(d)
    : "v"(p) : "memory");
}
// counted waits, tying the chunk's registers so LDS writes can't be hoisted
#define DEF_WAIT(NAME, N) \
__device__ __forceinline__ void NAME(i32x4& a, i32x4& b, i32x4& c, i32x4& d) { \
  asm volatile("s_waitcnt vmcnt(" #N ")" : "+v"(a), "+v"(b), "+v"(c), "+v"(d) :: "memory"); \
}
DEF_WAIT(wait_vm12, 12)
DEF_WAIT(wait_vm8, 8)
DEF_WAIT(wait_vm4, 4)
DEF_WAIT(wait_vm0, 0)

__device__ __forceinline__ void wr16(short* p, i32x4 v) {  // 16 B to LDS as 2x b64
  u32x2 lo, hi;
  lo.x = (unsigned)v.x; lo.y = (unsigned)v.y;
  hi.x = (unsigned)v.z; hi.y = (unsigned)v.w;
  *(u32x2*)p = lo;
  *(u32x2*)(p + 4) = hi;
}
__device__ __forceinline__ bf16x8 ld8(const short* p) {    // 8 bf16 from LDS as 2x b64
  union { bf16x8 v8; s16x4 h[2]; } u;
  u.h[0] = *(const s16x4*)p;
  u.h[1] = *(const s16x4*)(p + 4);
  return u.v8;
}
__device__ __forceinline__ float tanh_fast(float z) {
  float e = __expf(2.f * z);
  return 1.f - 2.f / (e + 1.f);
}

__device__ __forceinline__ void mfma_chunk(const short* sW, const short* sS,
                                           int wv, int l15, int quad, int c,
                                           f32x4& acc0, f32x4& acc1) {
  const short* Brow  = sW + (wv * 16 + l15) * WSTR + c * KC + quad * 8;
  const short* Arow0 = sS + l15 * SSTR + quad * 8;
  const short* Arow1 = Arow0 + 16 * SSTR;
#pragma unroll
  for (int ks = 0; ks < 8; ++ks) {
    bf16x8 bfr = ld8(Brow  + ks * 32);
    bf16x8 a0  = ld8(Arow0 + ks * 32);
    bf16x8 a1  = ld8(Arow1 + ks * 32);
    acc0 = __builtin_amdgcn_mfma_f32_16x16x32_bf16(a0, bfr, acc0, 0, 0, 0);
    acc1 = __builtin_amdgcn_mfma_f32_16x16x32_bf16(a1, bfr, acc1, 0, 0, 0);
  }
}

__global__ void __launch_bounds__(256, 1)
rnn_persistent(const float* __restrict__ x, const float* __restrict__ Whx,
               const float* __restrict__ Whh, const float* __restrict__ bh,
               const float* __restrict__ Wph, const float* __restrict__ bp,
               float* __restrict__ out, unsigned short* hbuf, int* flags)
{
  extern __shared__ short smem[];
  short* sW = smem;                 // [JT][WSTR] bf16 W_hh slice, persistent
  short* sS = smem + JT * WSTR;     // [BT][SSTR] bf16 h k-chunk stage (+ hS overlay)

  const int tid  = threadIdx.x;
  const int bg   = blockIdx.x & 15;
  const int jg   = blockIdx.x >> 4;
  const int lane = tid & 63;
  const int wv   = tid >> 6;          // wave = n-tile (16 cols each)
  const int l15  = lane & 15;
  const int quad = lane >> 4;

  // ---- stage W_hh[jg*64 .. +64)[0..1024) into LDS as bf16 ----
  {
    const int jr = tid >> 2;
    const int kq = tid & 3;
    const float* src = Whh + (jg * JT + jr) * HID + kq * 256;
    short* dst = sW + jr * WSTR + kq * 256;
#pragma unroll 4
    for (int i = 0; i < 64; ++i) {
      float4 f = *(const float4*)(src + i * 4);
      s16x4 h4;
      h4.x = (short)f2bf(f.x); h4.y = (short)f2bf(f.y);
      h4.z = (short)f2bf(f.z); h4.w = (short)f2bf(f.w);
      *(s16x4*)(dst + i * 4) = h4;
    }
  }

  const int j = jg * JT + wv * 16 + l15;       // per-lane output column
  const float whx = Whx[j];
  const float bhv = bh[j];
  const int grow0 = bg * BT + quad * 4;        // global batch row base (acc row group 0)

  // staging thread mapping: 64 B per thread per chunk
  const int sr  = tid >> 3;               // 0..31 stage row
  const int seg = tid & 7;                // 0..7

  int* myflags = flags + bg * 64;         // 16 flags, one 64B line per bg

  for (int t = 0; t < SEQ; ++t) {
    const unsigned short* hin = hbuf + ((t + 1) & 1) * HBUF_HALVES;
    unsigned short*      hout = hbuf + (t & 1) * HBUF_HALVES;

    f32x4 acc0 = {0.f, 0.f, 0.f, 0.f};
    f32x4 acc1 = {0.f, 0.f, 0.f, 0.f};

    // x for this step (independent of peers) — issued before the spin,
    // drained by the spin/syncthreads so the vmcnt window below is clean.
    float xv0[4], xv1[4];
    {
      const float* xp = x + grow0 * SEQ + t;
#pragma unroll
      for (int rg = 0; rg < 4; ++rg) {
        xv0[rg] = xp[rg * SEQ];
        xv1[rg] = xp[(16 + rg) * SEQ];
      }
    }

    if (t > 0) {
      // wait for all 16 peers of this batch-group to finish step t-1
      if (tid < GJ) {
        while (load_flag(myflags + tid) < t) {}
      }
      __syncthreads();   // full drain: vmcnt==0 entering the issue window

      const char* lbase = (const char*)(hin + (bg * BT + sr) * HID) + seg * 16;
      short* sdst = sS + sr * SSTR + seg * 8;

      i32x4 a0, a1, a2, a3, b0, b1, b2, b3, c0, c1, c2, c3, d0, d1, d2, d3;
      issue4(lbase,        a0, a1, a2, a3);   // chunk 0
      issue4(lbase + 512,  b0, b1, b2, b3);   // chunk 1
      issue4(lbase + 1024, c0, c1, c2, c3);   // chunk 2
      issue4(lbase + 1536, d0, d1, d2, d3);   // chunk 3

      // chunk 0 (stage free: post-spin __syncthreads was the barrier)
      wait_vm12(a0, a1, a2, a3);
      wr16(sdst, a0); wr16(sdst + 64, a1); wr16(sdst + 128, a2); wr16(sdst + 192, a3);
      barrier_lgkm();
      mfma_chunk(sW, sS, wv, l15, quad, 0, acc0, acc1);

      // chunk 1
      barrier_lgkm();                          // all waves done reading chunk 0
      wait_vm8(b0, b1, b2, b3);
      wr16(sdst, b0); wr16(sdst + 64, b1); wr16(sdst + 128, b2); wr16(sdst + 192, b3);
      barrier_lgkm();
      mfma_chunk(sW, sS, wv, l15, quad, 1, acc0, acc1);

      // chunk 2
      barrier_lgkm();
      wait_vm4(c0, c1, c2, c3);
      wr16(sdst, c0); wr16(sdst + 64, c1); wr16(sdst + 128, c2); wr16(sdst + 192, c3);
      barrier_lgkm();
      mfma_chunk(sW, sS, wv, l15, quad, 2, acc0, acc1);

      // chunk 3
      barrier_lgkm();
      wait_vm0(d0, d1, d2, d3);
      wr16(sdst, d0); wr16(sdst + 64, d1); wr16(sdst + 128, d2); wr16(sdst + 192, d3);
      barrier_lgkm();
      mfma_chunk(sW, sS, wv, l15, quad, 3, acc0, acc1);
    }

    // ---- epilogue: h = tanh(acc + x*whx + bh), exchange via LDS, coalesced store ----
    barrier_lgkm();     // chunk-3 stage reads done everywhere (sS reused as hS)
    {
      short* hS = sS;   // [BT][HSTR] overlay
#pragma unroll
      for (int rg = 0; rg < 4; ++rg) {
        float z0 = acc0[rg] + xv0[rg] * whx + bhv;
        hS[(quad * 4 + rg) * HSTR + wv * 16 + l15] = (short)f2bf(tanh_fast(z0));
        float z1 = acc1[rg] + xv1[rg] * whx + bhv;
        hS[(16 + quad * 4 + rg) * HSTR + wv * 16 + l15] = (short)f2bf(tanh_fast(z1));
      }
    }
    barrier_lgkm();
    {
      const short* hsrc = sS + sr * HSTR + seg * 8;
      u32x2 lo = *(const u32x2*)(hsrc);
      u32x2 hi = *(const u32x2*)(hsrc + 4);
      i32x4 sv; sv.x = (int)lo.x; sv.y = (int)lo.y; sv.z = (int)hi.x; sv.w = (int)hi.y;
      unsigned short* dst = hout + (bg * BT + sr) * HID + jg * JT + seg * 8;
      store16(dst, sv);
    }
    waitcnt0();          // this thread's 4KB-coalesced store retired at IC
    barrier_lgkm();      // all threads retired before the flag release
    if (tid == 0) store_flag(myflags + jg, t + 1);
  }

  // ---- output head: out[b, jg*8+cc] = h_last . W_ph[c] + b_p ----
  if (tid < GJ) {
    while (load_flag(myflags + tid) < SEQ) {}
  }
  __syncthreads();

  const unsigned short* hlast = hbuf + ((SEQ - 1) & 1) * HBUF_HALVES;
  const int cc = tid & 7;
  const int cg = jg * 8 + cc;
  const int hr = tid >> 3;
  float acc = 0.f;
  const char* lbase = (const char*)(hlast + (bg * BT + sr) * HID) + seg * 16;
  short* sdst = sS + sr * SSTR + seg * 8;
  for (int c = 0; c < 4; ++c) {
    __syncthreads();
    i32x4 p0, p1, p2, p3;
    issue4(lbase + c * 512, p0, p1, p2, p3);
    waitcnt0();
    wr16(sdst, p0); wr16(sdst + 64, p1); wr16(sdst + 128, p2); wr16(sdst + 192, p3);
    __syncthreads();
    const float* wp = Wph + cg * HID + c * KC;
    const short* hs = sS + hr * SSTR;
#pragma unroll 8
    for (int k4 = 0; k4 < 64; ++k4) {
      float4 w  = *(const float4*)(wp + k4 * 4);
      s16x4 hv  = *(const s16x4*)(hs + k4 * 4);
      acc += b2f(hv.x) * w.x + b2f(hv.y) * w.y + b2f(hv.z) * w.z + b2f(hv.w) * w.w;
    }
  }
  out[(bg * BT + hr) * CLS + cg] = acc + bp[cg];
}

extern "C" void kernel_launch(void* const* d_in, const int* in_sizes, int n_in,
                              void* d_out, int out_size, void* d_ws, size_t ws_size,
                              hipStream_t stream) {
  const float* x   = (const float*)d_in[0];
  const float* Whx = (const float*)d_in[1];
  const float* Whh = (const float*)d_in[2];
  const float* bh  = (const float*)d_in[3];
  const float* Wph = (const float*)d_in[4];
  const float* bp  = (const float*)d_in[5];
  float* out = (float*)d_out;

  unsigned short* hbuf = (unsigned short*)d_ws;
  int* flags = (int*)((char*)d_ws + (size_t)2 * HBUF_HALVES * 2);

  hipFuncSetAttribute(reinterpret_cast<const void*>(rnn_persistent),
                      hipFuncAttributeMaxDynamicSharedMemorySize, SMEM_BYTES);

  rnn_persistent<<<dim3(GB * GJ), dim3(256), SMEM_BYTES, stream>>>(
      x, Whx, Whh, bh, Wph, bp, out, hbuf, flags);
}